// Round 2
// baseline (2482.848 us; speedup 1.0000x reference)
//
#include <hip/hip_runtime.h>
#include <stdint.h>

// ---- problem constants ----
#define NWIN 200     // 8 images * 5*5 windows
#define LW   196     // 14*14 tokens per window
#define NTOK 32768   // 8*64*64
#define CDIM 768
#define GIMG 2       // images per group
#define NGRP 4       // 8 / GIMG
#define GWIN (GIMG * 25)          // 50 windows per group
#define MG   (GWIN * LW)          // 9800 rows per group
#define MLPCH 8192                // MLP chunk rows

typedef short bf16x8 __attribute__((ext_vector_type(8)));
typedef float f32x4  __attribute__((ext_vector_type(4)));

static __device__ __forceinline__ short f2bf(float f) {
  union { float f; uint32_t u; } v; v.f = f;
  uint32_t r = (v.u + 0x7fffu + ((v.u >> 16) & 1u)) >> 16;
  return (short)(uint16_t)r;
}
static __device__ __forceinline__ float bf2f(short s) {
  union { uint32_t u; float f; } v; v.u = ((uint32_t)(uint16_t)s) << 16;
  return v.f;
}

// async global->LDS, 16B per lane; lds base must be wave-uniform.
static __device__ __forceinline__ void async16(void* lds, const void* g) {
  __builtin_amdgcn_global_load_lds(
      (const __attribute__((address_space(1))) uint32_t*)g,
      (__attribute__((address_space(3))) uint32_t*)lds, 16, 0, 0);
}

// ---- weight transpose + cvt: in fp32 (K,N) row-major -> out bf16 (N,K) ----
__global__ __launch_bounds__(256) void k_transpose_cvt(
    const float* __restrict__ in, short* __restrict__ out, int K, int N) {
  __shared__ float t[32][33];
  int tx = threadIdx.x & 31, ty = threadIdx.x >> 5;   // ty 0..7
  int n0 = blockIdx.x * 32, k0 = blockIdx.y * 32;
#pragma unroll
  for (int i = 0; i < 4; ++i)
    t[ty + i * 8][tx] = in[(size_t)(k0 + ty + i * 8) * N + n0 + tx];
  __syncthreads();
#pragma unroll
  for (int i = 0; i < 4; ++i)
    out[(size_t)(n0 + ty + i * 8) * K + k0 + tx] = f2bf(t[tx][ty + i * 8]);
}

// ---- LayerNorm (wave per token). WINDOWED: emit window-partitioned+padded rows ----
template <bool WINDOWED>
__global__ __launch_bounds__(256) void k_layernorm(
    const float* __restrict__ in, const float* __restrict__ gw,
    const float* __restrict__ gb, short* __restrict__ out, int img0) {
  int wave = threadIdx.x >> 6, lane = threadIdx.x & 63;
  int t = blockIdx.x * 4 + wave;
  bool valid = true;
  size_t src;
  if (WINDOWED) {
    int win = t / LW, l = t % LW;              // win local to group
    int bi = img0 + win / 25, rem = win % 25;
    int y = (rem / 5) * 14 + l / 14;
    int x = (rem % 5) * 14 + l % 14;
    valid = (y < 64) && (x < 64);
    src = ((size_t)bi * 4096 + (size_t)y * 64 + x) * CDIM;
  } else {
    src = (size_t)t * CDIM;
  }
  size_t dst = (size_t)t * CDIM;
  if (valid) {
    float v[12];
    float s = 0.f, sq = 0.f;
#pragma unroll
    for (int j = 0; j < 3; ++j) {
      float4 f = *(const float4*)&in[src + (size_t)(j * 64 + lane) * 4];
      v[j * 4 + 0] = f.x; v[j * 4 + 1] = f.y; v[j * 4 + 2] = f.z; v[j * 4 + 3] = f.w;
      s += f.x + f.y + f.z + f.w;
      sq += f.x * f.x + f.y * f.y + f.z * f.z + f.w * f.w;
    }
#pragma unroll
    for (int m = 1; m < 64; m <<= 1) { s += __shfl_xor(s, m); sq += __shfl_xor(sq, m); }
    float mean = s * (1.f / 768.f);
    float rstd = rsqrtf(sq * (1.f / 768.f) - mean * mean + 1e-5f);
#pragma unroll
    for (int j = 0; j < 3; ++j) {
      int e = (j * 64 + lane) * 4;
      float4 w4 = *(const float4*)&gw[e];
      float4 b4 = *(const float4*)&gb[e];
      uint2 pk;
      pk.x = (uint32_t)(uint16_t)f2bf((v[j*4+0] - mean) * rstd * w4.x + b4.x)
           | ((uint32_t)(uint16_t)f2bf((v[j*4+1] - mean) * rstd * w4.y + b4.y) << 16);
      pk.y = (uint32_t)(uint16_t)f2bf((v[j*4+2] - mean) * rstd * w4.z + b4.z)
           | ((uint32_t)(uint16_t)f2bf((v[j*4+3] - mean) * rstd * w4.w + b4.w) << 16);
      *(uint2*)&out[dst + e] = pk;
    }
  } else {
    uint2 z; z.x = 0u; z.y = 0u;
#pragma unroll
    for (int j = 0; j < 3; ++j)
      *(uint2*)&out[dst + (size_t)(j * 64 + lane) * 4] = z;
  }
}

// ---- TN GEMM: C(M,N) = A(M,K)bf16 @ Bt(N,K)bf16^T + bias, m97 structure ----
// MODE 0: store bf16                               (QKV)
// MODE 1: unpad-scatter, +extra resid, store fp32  (proj; img0 = group image base)
// MODE 2: GELU(exact), store bf16                  (MLP1)
// MODE 3: +extra resid, store fp32                 (MLP2 -> d_out; out/extra alias same index, safe)
template <int MODE>
__global__ __launch_bounds__(256, 2) void k_gemm(
    const short* __restrict__ A, const short* __restrict__ Bt,
    const float* __restrict__ bias, void* __restrict__ out,
    const float* __restrict__ extra, int M, int N, int K, int img0) {
  __shared__ short As[128 * 32];
  __shared__ short Bs[128 * 32];
  int tid = threadIdx.x;
  int wave = tid >> 6, lane = tid & 63;
  int wm = wave >> 1, wn = wave & 1;
  int ln = lane & 15, q8 = (lane >> 4) * 8;
  long bm = (long)blockIdx.y * 128, bn = (long)blockIdx.x * 128;
  f32x4 acc[4][4];
#pragma unroll
  for (int i = 0; i < 4; ++i)
#pragma unroll
    for (int j = 0; j < 4; ++j) acc[i][j] = f32x4{0.f, 0.f, 0.f, 0.f};
  int srow = lane >> 2;          // 0..15
  int scol = (lane & 3) * 8;     // 0,8,16,24
  for (int k0 = 0; k0 < K; k0 += 32) {
#pragma unroll
    for (int i = 0; i < 2; ++i) {
      int chunk = wave * 2 + i;
      long ra = bm + chunk * 16 + srow;
      if (ra > M - 1) ra = M - 1;               // clamp (dup rows; never stored)
      async16(&As[chunk * 512], A + ra * K + k0 + scol);
      long rb = bn + chunk * 16 + srow;         // N is multiple of 128
      async16(&Bs[chunk * 512], Bt + rb * K + k0 + scol);
    }
    __syncthreads();
    bf16x8 af[4], bfv[4];
#pragma unroll
    for (int t = 0; t < 4; ++t) {
      af[t]  = *(const bf16x8*)&As[(wm * 64 + t * 16 + ln) * 32 + q8];
      bfv[t] = *(const bf16x8*)&Bs[(wn * 64 + t * 16 + ln) * 32 + q8];
    }
#pragma unroll
    for (int mt = 0; mt < 4; ++mt)
#pragma unroll
      for (int nt = 0; nt < 4; ++nt)
        acc[mt][nt] = __builtin_amdgcn_mfma_f32_16x16x32_bf16(af[mt], bfv[nt], acc[mt][nt], 0, 0, 0);
    __syncthreads();
  }
  // epilogue: C row = (lane>>4)*4 + r, col = lane&15  [measured layout, m89/m91]
#pragma unroll
  for (int nt = 0; nt < 4; ++nt) {
    int col = (int)(bn + wn * 64 + nt * 16 + ln);
    float bb = bias[col];
#pragma unroll
    for (int mt = 0; mt < 4; ++mt) {
#pragma unroll
      for (int r = 0; r < 4; ++r) {
        long row = bm + wm * 64 + mt * 16 + (lane >> 4) * 4 + r;
        if (row >= M) continue;
        float v = acc[mt][nt][r] + bb;
        if (MODE == 0) {
          ((short*)out)[row * (long)N + col] = f2bf(v);
        } else if (MODE == 1) {
          int win = (int)(row / LW), l = (int)(row % LW);
          int bi = img0 + win / 25, rem = win % 25;
          int y = (rem / 5) * 14 + l / 14;
          int x = (rem % 5) * 14 + l % 14;
          if (y < 64 && x < 64) {
            size_t d = ((size_t)bi * 4096 + (size_t)y * 64 + x) * CDIM + col;
            ((float*)out)[d] = v + extra[d];
          }
        } else if (MODE == 2) {
          v = 0.5f * v * (1.f + erff(v * 0.70710678118f));
          ((short*)out)[row * (long)N + col] = f2bf(v);
        } else {
          size_t d = (size_t)row * N + col;
          ((float*)out)[d] = v + extra[d];
        }
      }
    }
  }
}

// ---- decomposed rel-pos bias tables (per group): bh[q][kh]=Q[q].Rh, bw[q][kw]=Q[q].Rw ----
__global__ __launch_bounds__(256) void k_relbias(
    const short* __restrict__ qkv, const float* __restrict__ relh,
    const float* __restrict__ relw, float* __restrict__ bhg, float* __restrict__ bwg) {
  __shared__ short Qs[LW * 64];
  int w = blockIdx.x / 12, h = blockIdx.x % 12;   // w local to group
  size_t base = (size_t)w * LW * 2304 + (size_t)h * 64;   // Q slice
  for (int i = threadIdx.x; i < LW * 8; i += 256) {
    int row = i >> 3, c = (i & 7) * 8;
    *(uint4*)&Qs[row * 64 + c] = *(const uint4*)&qkv[base + (size_t)row * 2304 + c];
  }
  __syncthreads();
  size_t obase = (size_t)blockIdx.x * (LW * 14);
  for (int d = threadIdx.x; d < 2 * LW * 14; d += 256) {
    int tbl = d / (LW * 14), r = d % (LW * 14);
    int q = r / 14, kt = r % 14;
    int qh = q / 14, qw = q % 14;
    const float* tab = tbl ? &relw[(qw - kt + 13) * 64] : &relh[(qh - kt + 13) * 64];
    float s = 0.f;
#pragma unroll
    for (int j8 = 0; j8 < 8; ++j8) {
      bf16x8 qv = *(const bf16x8*)&Qs[q * 64 + j8 * 8];
      float4 ta = *(const float4*)&tab[j8 * 8];
      float4 tb = *(const float4*)&tab[j8 * 8 + 4];
      s += bf2f(qv[0]) * ta.x + bf2f(qv[1]) * ta.y + bf2f(qv[2]) * ta.z + bf2f(qv[3]) * ta.w
         + bf2f(qv[4]) * tb.x + bf2f(qv[5]) * tb.y + bf2f(qv[6]) * tb.z + bf2f(qv[7]) * tb.w;
    }
    (tbl ? bwg : bhg)[obase + r] = s;
  }
}

// ---- attention: one block per (window, head) within group; 4 waves; LDS 57344B ----
__global__ __launch_bounds__(256, 2) void k_attn(
    const short* __restrict__ qkv, const float* __restrict__ bhg,
    const float* __restrict__ bwg, short* __restrict__ o) {
  __shared__ short Vt[64 * 224];        // V^T, zero-padded cols 196..223
  __shared__ short Ps[4][16 * 224];     // per-wave P tile (also V staging at start)
  int w = blockIdx.x / 12, h = blockIdx.x % 12;
  int wave = threadIdx.x >> 6, lane = threadIdx.x & 63;
  int ln = lane & 15, quad = lane >> 4;
  size_t qbase = (size_t)w * LW * 2304 + (size_t)h * 64;
  size_t kbase = qbase + 768;
  size_t vbase = qbase + 1536;
  // stage V row-major into Ps area, then transpose into Vt
  short* Vrm = &Ps[0][0];
  for (int i = threadIdx.x; i < LW * 8; i += 256) {
    int row = i >> 3, c = (i & 7) * 8;
    *(uint4*)&Vrm[row * 64 + c] = *(const uint4*)&qkv[vbase + (size_t)row * 2304 + c];
  }
  __syncthreads();
  for (int i = threadIdx.x; i < 64 * 224; i += 256) {
    int d = i / 224, l = i % 224;
    Vt[d * 224 + l] = (l < LW) ? Vrm[l * 64 + d] : (short)0;
  }
  __syncthreads();
  for (int i = lane; i < 16 * 224; i += 64) Ps[wave][i] = 0;   // own tile
  const float scale = 0.125f;
  size_t obh = (size_t)blockIdx.x * (LW * 14);
  for (int mt = wave; mt < 13; mt += 4) {
    bf16x8 aq[2];
    int qrow = mt * 16 + ln; if (qrow > LW - 1) qrow = LW - 1;
#pragma unroll
    for (int kk = 0; kk < 2; ++kk)
      aq[kk] = *(const bf16x8*)&qkv[qbase + (size_t)qrow * 2304 + kk * 32 + quad * 8];
    f32x4 s[13];
#pragma unroll
    for (int nt = 0; nt < 13; ++nt) {
      s[nt] = f32x4{0.f, 0.f, 0.f, 0.f};
      int krow = nt * 16 + ln; if (krow > LW - 1) krow = LW - 1;
#pragma unroll
      for (int kk = 0; kk < 2; ++kk) {
        bf16x8 bk = *(const bf16x8*)&qkv[kbase + (size_t)krow * 2304 + kk * 32 + quad * 8];
        s[nt] = __builtin_amdgcn_mfma_f32_16x16x32_bf16(aq[kk], bk, s[nt], 0, 0, 0);
      }
    }
    // scale + rel-pos bias + mask, then row softmax (rows span 16-lane groups)
    float rmax[4] = {-3e38f, -3e38f, -3e38f, -3e38f};
#pragma unroll
    for (int nt = 0; nt < 13; ++nt) {
      int c = nt * 16 + ln;
#pragma unroll
      for (int r = 0; r < 4; ++r) {
        int q = mt * 16 + quad * 4 + r;
        float v;
        if (c < LW && q < LW)
          v = s[nt][r] * scale + bhg[obh + q * 14 + c / 14] + bwg[obh + q * 14 + c % 14];
        else
          v = -1e30f;
        s[nt][r] = v;
        rmax[r] = fmaxf(rmax[r], v);
      }
    }
#pragma unroll
    for (int r = 0; r < 4; ++r)
#pragma unroll
      for (int m = 1; m < 16; m <<= 1) rmax[r] = fmaxf(rmax[r], __shfl_xor(rmax[r], m));
    float rsum[4] = {0.f, 0.f, 0.f, 0.f};
#pragma unroll
    for (int nt = 0; nt < 13; ++nt)
#pragma unroll
      for (int r = 0; r < 4; ++r) {
        float e = __expf(s[nt][r] - rmax[r]);
        s[nt][r] = e;
        rsum[r] += e;
      }
#pragma unroll
    for (int r = 0; r < 4; ++r) {
#pragma unroll
      for (int m = 1; m < 16; m <<= 1) rsum[r] += __shfl_xor(rsum[r], m);
      rsum[r] = 1.f / rsum[r];
    }
#pragma unroll
    for (int nt = 0; nt < 13; ++nt) {
      int c = nt * 16 + ln;
#pragma unroll
      for (int r = 0; r < 4; ++r) {
        int rowi = quad * 4 + r;
        int q = mt * 16 + rowi;
        float p = (q < LW) ? s[nt][r] * rsum[r] : 0.f;
        Ps[wave][rowi * 224 + c] = f2bf(p);
      }
    }
    // PV: O(16x64) += P(16x224) @ V(224x64); intra-wave LDS RAW (in-order LDS)
    f32x4 acc[4];
#pragma unroll
    for (int nt = 0; nt < 4; ++nt) acc[nt] = f32x4{0.f, 0.f, 0.f, 0.f};
#pragma unroll
    for (int ks = 0; ks < 7; ++ks) {
      bf16x8 ap = *(const bf16x8*)&Ps[wave][ln * 224 + ks * 32 + quad * 8];
#pragma unroll
      for (int nt = 0; nt < 4; ++nt) {
        bf16x8 bv = *(const bf16x8*)&Vt[(nt * 16 + ln) * 224 + ks * 32 + quad * 8];
        acc[nt] = __builtin_amdgcn_mfma_f32_16x16x32_bf16(ap, bv, acc[nt], 0, 0, 0);
      }
    }
#pragma unroll
    for (int nt = 0; nt < 4; ++nt)
#pragma unroll
      for (int r = 0; r < 4; ++r) {
        int q = mt * 16 + quad * 4 + r;
        if (q < LW)
          o[((size_t)w * LW + q) * CDIM + (size_t)h * 64 + nt * 16 + ln] = f2bf(acc[nt][r]);
      }
  }
}

extern "C" void kernel_launch(void* const* d_in, const int* in_sizes, int n_in,
                              void* d_out, int out_size, void* d_ws, size_t ws_size,
                              hipStream_t stream) {
  const float* x     = (const float*)d_in[0];
  const float* ln1w  = (const float*)d_in[1];
  const float* ln1b  = (const float*)d_in[2];
  const float* qkvw  = (const float*)d_in[3];
  const float* qkvb  = (const float*)d_in[4];
  const float* projw = (const float*)d_in[5];
  const float* projb = (const float*)d_in[6];
  const float* relh  = (const float*)d_in[7];
  const float* relw  = (const float*)d_in[8];
  const float* ln2w  = (const float*)d_in[9];
  const float* ln2b  = (const float*)d_in[10];
  const float* mlpw1 = (const float*)d_in[11];
  const float* mlpb1 = (const float*)d_in[12];
  const float* mlpw2 = (const float*)d_in[13];
  const float* mlpb2 = (const float*)d_in[14];

  char* ws = (char*)d_ws;
  size_t off = 0;
  auto alloc = [&](size_t bytes) {
    char* p = ws + off;
    off += (bytes + 255) & ~(size_t)255;
    return p;
  };
  // persistent weights (bf16, transposed)           ~14.2 MB
  short* wQKVt  = (short*)alloc((size_t)2304 * 768 * 2);
  short* wPROJt = (short*)alloc((size_t)768 * 768 * 2);
  short* wMLP1t = (short*)alloc((size_t)3072 * 768 * 2);
  short* wMLP2t = (short*)alloc((size_t)768 * 3072 * 2);
  // group loop region (reused per group; later aliased by MLP1 chunk)  ~73.4 MB
  char* loopBase = alloc((size_t)MG * CDIM * 2        // A_g / O_g
                       + (size_t)MG * 2304 * 2        // QKV_g
                       + (size_t)GWIN * 12 * LW * 14 * 4 * 2);  // bias tables
  short* wA   = (short*)loopBase;
  short* wQKV = (short*)(loopBase + (size_t)MG * CDIM * 2);
  float* wBH  = (float*)(loopBase + (size_t)MG * CDIM * 2 + (size_t)MG * 2304 * 2);
  float* wBW  = wBH + (size_t)GWIN * 12 * LW * 14;
  short* wO   = wA;                                   // O_g aliases A_g (dead after QKV GEMM)
  short* wMLP1 = (short*)loopBase;                    // MLP1 chunk aliases loop region (dead)
  // LN2 output (full batch)                          ~50.3 MB
  short* wH2  = (short*)alloc((size_t)NTOK * CDIM * 2);
  // fp32 residual x2 lives in d_out (exact size match; MODE-3 aliasing is same-index safe)
  float* wX2  = (float*)d_out;

  k_transpose_cvt<<<dim3(2304 / 32, 768 / 32), 256, 0, stream>>>(qkvw, wQKVt, 768, 2304);
  k_transpose_cvt<<<dim3(768 / 32, 768 / 32), 256, 0, stream>>>(projw, wPROJt, 768, 768);
  k_transpose_cvt<<<dim3(3072 / 32, 768 / 32), 256, 0, stream>>>(mlpw1, wMLP1t, 768, 3072);
  k_transpose_cvt<<<dim3(768 / 32, 3072 / 32), 256, 0, stream>>>(mlpw2, wMLP2t, 3072, 768);

  for (int g = 0; g < NGRP; ++g) {
    int img0 = g * GIMG;
    k_layernorm<true><<<MG / 4, 256, 0, stream>>>(x, ln1w, ln1b, wA, img0);
    k_gemm<0><<<dim3(2304 / 128, (MG + 127) / 128), 256, 0, stream>>>(
        wA, wQKVt, qkvb, wQKV, nullptr, MG, 2304, 768, 0);
    k_relbias<<<GWIN * 12, 256, 0, stream>>>(wQKV, relh, relw, wBH, wBW);
    k_attn<<<GWIN * 12, 256, 0, stream>>>(wQKV, wBH, wBW, wO);
    k_gemm<1><<<dim3(768 / 128, (MG + 127) / 128), 256, 0, stream>>>(
        wO, wPROJt, projb, wX2, x, MG, 768, 768, img0);
  }

  k_layernorm<false><<<NTOK / 4, 256, 0, stream>>>(wX2, ln2w, ln2b, wH2, 0);

  for (int c = 0; c < NTOK / MLPCH; ++c) {
    const short* h2c = wH2 + (size_t)c * MLPCH * CDIM;
    float* outc = (float*)d_out + (size_t)c * MLPCH * CDIM;
    k_gemm<2><<<dim3(3072 / 128, MLPCH / 128), 256, 0, stream>>>(
        h2c, wMLP1t, mlpb1, wMLP1, nullptr, MLPCH, 3072, 768, 0);
    k_gemm<3><<<dim3(768 / 128, MLPCH / 128), 256, 0, stream>>>(
        wMLP1, wMLP2t, mlpb2, outc, outc, MLPCH, 768, 3072, 0);
  }
}

// Round 3
// 2135.372 us; speedup vs baseline: 1.1627x; 1.1627x over previous
//
#include <hip/hip_runtime.h>
#include <stdint.h>

// ---- problem constants ----
#define NWIN 200     // 8 images * 5*5 windows
#define LW   196     // 14*14 tokens per window
#define NTOK 32768   // 8*64*64
#define CDIM 768
#define GIMG 2       // images per group
#define NGRP 4       // 8 / GIMG
#define GWIN (GIMG * 25)          // 50 windows per group
#define MG   (GWIN * LW)          // 9800 rows per group
#define MLPCH 8192                // MLP chunk rows

typedef short bf16x8 __attribute__((ext_vector_type(8)));
typedef float f32x4  __attribute__((ext_vector_type(4)));

static __device__ __forceinline__ short f2bf(float f) {
  union { float f; uint32_t u; } v; v.f = f;
  uint32_t r = (v.u + 0x7fffu + ((v.u >> 16) & 1u)) >> 16;
  return (short)(uint16_t)r;
}
static __device__ __forceinline__ float bf2f(short s) {
  union { uint32_t u; float f; } v; v.u = ((uint32_t)(uint16_t)s) << 16;
  return v.f;
}

// async global->LDS, 16B per lane; lds base must be wave-uniform.
static __device__ __forceinline__ void async16(void* lds, const void* g) {
  __builtin_amdgcn_global_load_lds(
      (const __attribute__((address_space(1))) uint32_t*)g,
      (__attribute__((address_space(3))) uint32_t*)lds, 16, 0, 0);
}

// ---- weight transpose + cvt: in fp32 (K,N) row-major -> out bf16 (N,K) ----
__global__ __launch_bounds__(256) void k_transpose_cvt(
    const float* __restrict__ in, short* __restrict__ out, int K, int N) {
  __shared__ float t[32][33];
  int tx = threadIdx.x & 31, ty = threadIdx.x >> 5;   // ty 0..7
  int n0 = blockIdx.x * 32, k0 = blockIdx.y * 32;
#pragma unroll
  for (int i = 0; i < 4; ++i)
    t[ty + i * 8][tx] = in[(size_t)(k0 + ty + i * 8) * N + n0 + tx];
  __syncthreads();
#pragma unroll
  for (int i = 0; i < 4; ++i)
    out[(size_t)(n0 + ty + i * 8) * K + k0 + tx] = f2bf(t[tx][ty + i * 8]);
}

// ---- LayerNorm (wave per token). WINDOWED: emit window-partitioned+padded rows ----
template <bool WINDOWED>
__global__ __launch_bounds__(256) void k_layernorm(
    const float* __restrict__ in, const float* __restrict__ gw,
    const float* __restrict__ gb, short* __restrict__ out, int img0) {
  int wave = threadIdx.x >> 6, lane = threadIdx.x & 63;
  int t = blockIdx.x * 4 + wave;
  bool valid = true;
  size_t src;
  if (WINDOWED) {
    int win = t / LW, l = t % LW;              // win local to group
    int bi = img0 + win / 25, rem = win % 25;
    int y = (rem / 5) * 14 + l / 14;
    int x = (rem % 5) * 14 + l % 14;
    valid = (y < 64) && (x < 64);
    src = ((size_t)bi * 4096 + (size_t)y * 64 + x) * CDIM;
  } else {
    src = (size_t)t * CDIM;
  }
  size_t dst = (size_t)t * CDIM;
  if (valid) {
    float v[12];
    float s = 0.f, sq = 0.f;
#pragma unroll
    for (int j = 0; j < 3; ++j) {
      float4 f = *(const float4*)&in[src + (size_t)(j * 64 + lane) * 4];
      v[j * 4 + 0] = f.x; v[j * 4 + 1] = f.y; v[j * 4 + 2] = f.z; v[j * 4 + 3] = f.w;
      s += f.x + f.y + f.z + f.w;
      sq += f.x * f.x + f.y * f.y + f.z * f.z + f.w * f.w;
    }
#pragma unroll
    for (int m = 1; m < 64; m <<= 1) { s += __shfl_xor(s, m); sq += __shfl_xor(sq, m); }
    float mean = s * (1.f / 768.f);
    float rstd = rsqrtf(sq * (1.f / 768.f) - mean * mean + 1e-5f);
#pragma unroll
    for (int j = 0; j < 3; ++j) {
      int e = (j * 64 + lane) * 4;
      float4 w4 = *(const float4*)&gw[e];
      float4 b4 = *(const float4*)&gb[e];
      uint2 pk;
      pk.x = (uint32_t)(uint16_t)f2bf((v[j*4+0] - mean) * rstd * w4.x + b4.x)
           | ((uint32_t)(uint16_t)f2bf((v[j*4+1] - mean) * rstd * w4.y + b4.y) << 16);
      pk.y = (uint32_t)(uint16_t)f2bf((v[j*4+2] - mean) * rstd * w4.z + b4.z)
           | ((uint32_t)(uint16_t)f2bf((v[j*4+3] - mean) * rstd * w4.w + b4.w) << 16);
      *(uint2*)&out[dst + e] = pk;
    }
  } else {
    uint2 z; z.x = 0u; z.y = 0u;
#pragma unroll
    for (int j = 0; j < 3; ++j)
      *(uint2*)&out[dst + (size_t)(j * 64 + lane) * 4] = z;
  }
}

// ---- TN GEMM: C(M,N) = A(M,K)bf16 @ Bt(N,K)bf16^T + bias, m97 structure ----
// MODE 0: store bf16                               (QKV)
// MODE 1: unpad-scatter, +extra resid, store fp32  (proj; img0 = group image base)
// MODE 2: GELU(exact), store bf16                  (MLP1)
// MODE 3: +extra resid, store fp32                 (MLP2 -> d_out; out/extra alias same index, safe)
template <int MODE>
__global__ __launch_bounds__(256, 2) void k_gemm(
    const short* __restrict__ A, const short* __restrict__ Bt,
    const float* __restrict__ bias, void* __restrict__ out,
    const float* __restrict__ extra, int M, int N, int K, int img0) {
  __shared__ short As[128 * 32];
  __shared__ short Bs[128 * 32];
  int tid = threadIdx.x;
  int wave = tid >> 6, lane = tid & 63;
  int wm = wave >> 1, wn = wave & 1;
  int ln = lane & 15, q8 = (lane >> 4) * 8;
  long bm = (long)blockIdx.y * 128, bn = (long)blockIdx.x * 128;
  f32x4 acc[4][4];
#pragma unroll
  for (int i = 0; i < 4; ++i)
#pragma unroll
    for (int j = 0; j < 4; ++j) acc[i][j] = f32x4{0.f, 0.f, 0.f, 0.f};
  int srow = lane >> 2;          // 0..15
  int scol = (lane & 3) * 8;     // 0,8,16,24
  for (int k0 = 0; k0 < K; k0 += 32) {
#pragma unroll
    for (int i = 0; i < 2; ++i) {
      int chunk = wave * 2 + i;
      long ra = bm + chunk * 16 + srow;
      if (ra > M - 1) ra = M - 1;               // clamp (dup rows; never stored)
      async16(&As[chunk * 512], A + ra * K + k0 + scol);
      long rb = bn + chunk * 16 + srow;         // N is multiple of 128
      async16(&Bs[chunk * 512], Bt + rb * K + k0 + scol);
    }
    __syncthreads();
    bf16x8 af[4], bfv[4];
#pragma unroll
    for (int t = 0; t < 4; ++t) {
      af[t]  = *(const bf16x8*)&As[(wm * 64 + t * 16 + ln) * 32 + q8];
      bfv[t] = *(const bf16x8*)&Bs[(wn * 64 + t * 16 + ln) * 32 + q8];
    }
#pragma unroll
    for (int mt = 0; mt < 4; ++mt)
#pragma unroll
      for (int nt = 0; nt < 4; ++nt)
        acc[mt][nt] = __builtin_amdgcn_mfma_f32_16x16x32_bf16(af[mt], bfv[nt], acc[mt][nt], 0, 0, 0);
    __syncthreads();
  }
  // epilogue: C row = (lane>>4)*4 + r, col = lane&15  [measured layout, m89/m91]
#pragma unroll
  for (int nt = 0; nt < 4; ++nt) {
    int col = (int)(bn + wn * 64 + nt * 16 + ln);
    float bb = bias[col];
#pragma unroll
    for (int mt = 0; mt < 4; ++mt) {
#pragma unroll
      for (int r = 0; r < 4; ++r) {
        long row = bm + wm * 64 + mt * 16 + (lane >> 4) * 4 + r;
        if (row >= M) continue;
        float v = acc[mt][nt][r] + bb;
        if (MODE == 0) {
          ((short*)out)[row * (long)N + col] = f2bf(v);
        } else if (MODE == 1) {
          int win = (int)(row / LW), l = (int)(row % LW);
          int bi = img0 + win / 25, rem = win % 25;
          int y = (rem / 5) * 14 + l / 14;
          int x = (rem % 5) * 14 + l % 14;
          if (y < 64 && x < 64) {
            size_t d = ((size_t)bi * 4096 + (size_t)y * 64 + x) * CDIM + col;
            ((float*)out)[d] = v + extra[d];
          }
        } else if (MODE == 2) {
          v = 0.5f * v * (1.f + erff(v * 0.70710678118f));
          ((short*)out)[row * (long)N + col] = f2bf(v);
        } else {
          size_t d = (size_t)row * N + col;
          ((float*)out)[d] = v + extra[d];
        }
      }
    }
  }
}

// ---- decomposed rel-pos bias tables (bf16): per head block of 5488B:
// [0..2744) bh[q][kh], [2744..5488) bw[q][kw] ----
__global__ __launch_bounds__(256) void k_relbias(
    const short* __restrict__ qkv, const float* __restrict__ relh,
    const float* __restrict__ relw, short* __restrict__ bias_out) {
  __shared__ short Qs[LW * 64];
  int w = blockIdx.x / 12, h = blockIdx.x % 12;   // w local to group
  size_t base = (size_t)w * LW * 2304 + (size_t)h * 64;   // Q slice
  for (int i = threadIdx.x; i < LW * 8; i += 256) {
    int row = i >> 3, c = (i & 7) * 8;
    *(uint4*)&Qs[row * 64 + c] = *(const uint4*)&qkv[base + (size_t)row * 2304 + c];
  }
  __syncthreads();
  short* dst = bias_out + (size_t)blockIdx.x * 5488;
  for (int d = threadIdx.x; d < 2 * LW * 14; d += 256) {
    int tbl = d / (LW * 14), r = d % (LW * 14);
    int q = r / 14, kt = r % 14;
    int qh = q / 14, qw = q % 14;
    const float* tab = tbl ? &relw[(qw - kt + 13) * 64] : &relh[(qh - kt + 13) * 64];
    float s = 0.f;
#pragma unroll
    for (int j8 = 0; j8 < 8; ++j8) {
      bf16x8 qv = *(const bf16x8*)&Qs[q * 64 + j8 * 8];
      float4 ta = *(const float4*)&tab[j8 * 8];
      float4 tb = *(const float4*)&tab[j8 * 8 + 4];
      s += bf2f(qv[0]) * ta.x + bf2f(qv[1]) * ta.y + bf2f(qv[2]) * ta.z + bf2f(qv[3]) * ta.w
         + bf2f(qv[4]) * tb.x + bf2f(qv[5]) * tb.y + bf2f(qv[6]) * tb.z + bf2f(qv[7]) * tb.w;
    }
    dst[tbl * 2744 + r] = f2bf(s);
  }
}

// ---- attention v2: one block per (window, head); 4 waves; LDS 65040B ----
// LDS layout (shorts):
//   [0 .. 13720)        staging Vrm 196x70   -> later Ps: 4 waves x 16x208 (13312)
//   [13720 .. 27032)    Vt: 64x208
//   [27032 .. 32520)    bias bf16: bh 196x14, bw 196x14
__global__ __launch_bounds__(256, 2) void k_attn(
    const short* __restrict__ qkv, const short* __restrict__ bias_bf,
    short* __restrict__ o) {
  __shared__ short lds[32520];
  short* PsBase = lds;
  short* Vrm    = lds;
  short* Vt     = lds + 13720;
  short* Bh     = lds + 27032;
  short* Bw     = Bh + 2744;
  int tid = threadIdx.x;
  int w = blockIdx.x / 12, h = blockIdx.x % 12;
  int wave = tid >> 6, lane = tid & 63;
  int ln = lane & 15, quad = lane >> 4;
  size_t qbase = (size_t)w * LW * 2304 + (size_t)h * 64;
  size_t kbase = qbase + 768;
  size_t vbase = qbase + 1536;

  // stage V row-major into Vrm (stride 70; b32 writes, 4B-aligned always)
  for (int i = tid; i < LW * 8; i += 256) {
    int row = i >> 3, c = (i & 7) * 8;
    uint4 f = *(const uint4*)&qkv[vbase + (size_t)row * 2304 + c];
    uint32_t* dst = (uint32_t*)&Vrm[row * 70 + c];
    dst[0] = f.x; dst[1] = f.y; dst[2] = f.z; dst[3] = f.w;
  }
  // stage bias tables (686 * 16B)
  {
    const short* bt = bias_bf + (size_t)blockIdx.x * 5488;
    for (int i = tid; i < 686; i += 256)
      *(uint4*)&Bh[i * 8] = *(const uint4*)&bt[i * 8];
  }
  __syncthreads();
  // transpose: Vt[d*208+l] = Vrm[l*70+d]; read stride 35 dwords -> conflict-free
  for (int i = tid; i < 64 * 208; i += 256) {
    int d = i / 208, l = i % 208;
    Vt[i] = (l < LW) ? Vrm[l * 70 + d] : (short)0;
  }
  __syncthreads();

  short* Ps = PsBase + wave * (16 * 208);
  const float scale = 0.125f;
  for (int mt = wave; mt < 13; mt += 4) {
    bf16x8 aq[2];
    int qrow = mt * 16 + ln; if (qrow > LW - 1) qrow = LW - 1;
#pragma unroll
    for (int kk = 0; kk < 2; ++kk)
      aq[kk] = *(const bf16x8*)&qkv[qbase + (size_t)qrow * 2304 + kk * 32 + quad * 8];
    f32x4 s[13];
#pragma unroll
    for (int nt = 0; nt < 13; ++nt) {
      s[nt] = f32x4{0.f, 0.f, 0.f, 0.f};
      int krow = nt * 16 + ln; if (krow > LW - 1) krow = LW - 1;
#pragma unroll
      for (int kk = 0; kk < 2; ++kk) {
        bf16x8 bk = *(const bf16x8*)&qkv[kbase + (size_t)krow * 2304 + kk * 32 + quad * 8];
        s[nt] = __builtin_amdgcn_mfma_f32_16x16x32_bf16(aq[kk], bk, s[nt], 0, 0, 0);
      }
    }
    // scale + bias (from LDS) + mask; then row softmax (rows span 16-lane groups)
    float rmax[4] = {-3e38f, -3e38f, -3e38f, -3e38f};
#pragma unroll
    for (int nt = 0; nt < 13; ++nt) {
      int c = nt * 16 + ln;
      int cdiv = (c * 4682) >> 16;      // c/14 for c<=223
      int cmod = c - cdiv * 14;
#pragma unroll
      for (int r = 0; r < 4; ++r) {
        int q = mt * 16 + quad * 4 + r;
        int qc = q > LW - 1 ? LW - 1 : q;
        float v;
        if (c < LW && q < LW)
          v = s[nt][r] * scale + bf2f(Bh[qc * 14 + cdiv]) + bf2f(Bw[qc * 14 + cmod]);
        else
          v = -1e30f;
        s[nt][r] = v;
        rmax[r] = fmaxf(rmax[r], v);
      }
    }
#pragma unroll
    for (int r = 0; r < 4; ++r)
#pragma unroll
      for (int m = 1; m < 16; m <<= 1) rmax[r] = fmaxf(rmax[r], __shfl_xor(rmax[r], m));
    float rsum[4] = {0.f, 0.f, 0.f, 0.f};
#pragma unroll
    for (int nt = 0; nt < 13; ++nt)
#pragma unroll
      for (int r = 0; r < 4; ++r) {
        float e = __expf(s[nt][r] - rmax[r]);
        s[nt][r] = e;
        rsum[r] += e;
      }
#pragma unroll
    for (int r = 0; r < 4; ++r) {
#pragma unroll
      for (int m = 1; m < 16; m <<= 1) rsum[r] += __shfl_xor(rsum[r], m);
      rsum[r] = 1.f / rsum[r];
    }
    // P tile -> LDS (bf16), cols 0..207 all written (>=196 are exp(-inf)=0)
#pragma unroll
    for (int nt = 0; nt < 13; ++nt) {
      int c = nt * 16 + ln;
#pragma unroll
      for (int r = 0; r < 4; ++r) {
        int rowi = quad * 4 + r;
        int q = mt * 16 + rowi;
        float p = (q < LW) ? s[nt][r] * rsum[r] : 0.f;
        Ps[rowi * 208 + c] = f2bf(p);
      }
    }
    // PV: O(16x64) += P(16x208) @ V^T(208x64); intra-wave LDS RAW (in-order LDS)
    f32x4 acc[4];
#pragma unroll
    for (int nt = 0; nt < 4; ++nt) acc[nt] = f32x4{0.f, 0.f, 0.f, 0.f};
#pragma unroll
    for (int ks = 0; ks < 6; ++ks) {
      bf16x8 ap = *(const bf16x8*)&Ps[ln * 208 + ks * 32 + quad * 8];
#pragma unroll
      for (int nt = 0; nt < 4; ++nt) {
        bf16x8 bv = *(const bf16x8*)&Vt[(nt * 16 + ln) * 208 + ks * 32 + quad * 8];
        acc[nt] = __builtin_amdgcn_mfma_f32_16x16x32_bf16(ap, bv, acc[nt], 0, 0, 0);
      }
    }
    {
      // tail: cols 192..207 = k 0..15 of a 32-wide step -> quads 0,1 real, quads 2,3 zero
      bf16x8 zz = bf16x8{0,0,0,0,0,0,0,0};
      bf16x8 ap = (quad < 2) ? *(const bf16x8*)&Ps[ln * 208 + 192 + quad * 8] : zz;
#pragma unroll
      for (int nt = 0; nt < 4; ++nt) {
        bf16x8 bv = (quad < 2) ? *(const bf16x8*)&Vt[(nt * 16 + ln) * 208 + 192 + quad * 8] : zz;
        acc[nt] = __builtin_amdgcn_mfma_f32_16x16x32_bf16(ap, bv, acc[nt], 0, 0, 0);
      }
    }
#pragma unroll
    for (int nt = 0; nt < 4; ++nt)
#pragma unroll
      for (int r = 0; r < 4; ++r) {
        int q = mt * 16 + quad * 4 + r;
        if (q < LW)
          o[((size_t)w * LW + q) * CDIM + (size_t)h * 64 + nt * 16 + ln] = f2bf(acc[nt][r]);
      }
  }
}

extern "C" void kernel_launch(void* const* d_in, const int* in_sizes, int n_in,
                              void* d_out, int out_size, void* d_ws, size_t ws_size,
                              hipStream_t stream) {
  const float* x     = (const float*)d_in[0];
  const float* ln1w  = (const float*)d_in[1];
  const float* ln1b  = (const float*)d_in[2];
  const float* qkvw  = (const float*)d_in[3];
  const float* qkvb  = (const float*)d_in[4];
  const float* projw = (const float*)d_in[5];
  const float* projb = (const float*)d_in[6];
  const float* relh  = (const float*)d_in[7];
  const float* relw  = (const float*)d_in[8];
  const float* ln2w  = (const float*)d_in[9];
  const float* ln2b  = (const float*)d_in[10];
  const float* mlpw1 = (const float*)d_in[11];
  const float* mlpb1 = (const float*)d_in[12];
  const float* mlpw2 = (const float*)d_in[13];
  const float* mlpb2 = (const float*)d_in[14];

  char* ws = (char*)d_ws;
  size_t off = 0;
  auto alloc = [&](size_t bytes) {
    char* p = ws + off;
    off += (bytes + 255) & ~(size_t)255;
    return p;
  };
  // persistent weights (bf16, transposed)           ~14.2 MB
  short* wQKVt  = (short*)alloc((size_t)2304 * 768 * 2);
  short* wPROJt = (short*)alloc((size_t)768 * 768 * 2);
  short* wMLP1t = (short*)alloc((size_t)3072 * 768 * 2);
  short* wMLP2t = (short*)alloc((size_t)768 * 3072 * 2);
  // group loop region (reused per group; later aliased by MLP1 chunk)  ~67 MB
  char* loopBase = alloc((size_t)MG * CDIM * 2        // A_g / O_g
                       + (size_t)MG * 2304 * 2        // QKV_g
                       + (size_t)GWIN * 12 * 5488 * 2);  // bf16 bias tables
  short* wA    = (short*)loopBase;
  short* wQKV  = (short*)(loopBase + (size_t)MG * CDIM * 2);
  short* wBIAS = (short*)(loopBase + (size_t)MG * CDIM * 2 + (size_t)MG * 2304 * 2);
  short* wO    = wA;                                  // O_g aliases A_g (dead after QKV GEMM)
  short* wMLP1 = (short*)loopBase;                    // MLP1 chunk aliases loop region (dead)
  // LN2 output (full batch)                          ~50.3 MB
  short* wH2  = (short*)alloc((size_t)NTOK * CDIM * 2);
  // fp32 residual x2 lives in d_out (exact size match; MODE-3 aliasing is same-index safe)
  float* wX2  = (float*)d_out;

  k_transpose_cvt<<<dim3(2304 / 32, 768 / 32), 256, 0, stream>>>(qkvw, wQKVt, 768, 2304);
  k_transpose_cvt<<<dim3(768 / 32, 768 / 32), 256, 0, stream>>>(projw, wPROJt, 768, 768);
  k_transpose_cvt<<<dim3(3072 / 32, 768 / 32), 256, 0, stream>>>(mlpw1, wMLP1t, 768, 3072);
  k_transpose_cvt<<<dim3(768 / 32, 3072 / 32), 256, 0, stream>>>(mlpw2, wMLP2t, 3072, 768);

  for (int g = 0; g < NGRP; ++g) {
    int img0 = g * GIMG;
    k_layernorm<true><<<MG / 4, 256, 0, stream>>>(x, ln1w, ln1b, wA, img0);
    k_gemm<0><<<dim3(2304 / 128, (MG + 127) / 128), 256, 0, stream>>>(
        wA, wQKVt, qkvb, wQKV, nullptr, MG, 2304, 768, 0);
    k_relbias<<<GWIN * 12, 256, 0, stream>>>(wQKV, relh, relw, wBIAS);
    k_attn<<<GWIN * 12, 256, 0, stream>>>(wQKV, wBIAS, wO);
    k_gemm<1><<<dim3(768 / 128, (MG + 127) / 128), 256, 0, stream>>>(
        wO, wPROJt, projb, wX2, x, MG, 768, 768, img0);
  }

  k_layernorm<false><<<NTOK / 4, 256, 0, stream>>>(wX2, ln2w, ln2b, wH2, 0);

  for (int c = 0; c < NTOK / MLPCH; ++c) {
    const short* h2c = wH2 + (size_t)c * MLPCH * CDIM;
    float* outc = (float*)d_out + (size_t)c * MLPCH * CDIM;
    k_gemm<2><<<dim3(3072 / 128, MLPCH / 128), 256, 0, stream>>>(
        h2c, wMLP1t, mlpb1, wMLP1, nullptr, MLPCH, 3072, 768, 0);
    k_gemm<3><<<dim3(768 / 128, MLPCH / 128), 256, 0, stream>>>(
        wMLP1, wMLP2t, mlpb2, outc, outc, MLPCH, 768, 3072, 0);
  }
}

// Round 4
// 1699.830 us; speedup vs baseline: 1.4606x; 1.2562x over previous
//
#include <hip/hip_runtime.h>
#include <stdint.h>

// ---- problem constants ----
#define NWIN 200     // 8 images * 5*5 windows
#define LW   196     // 14*14 tokens per window
#define NTOK 32768   // 8*64*64
#define CDIM 768
#define GIMG 2       // images per group
#define NGRP 4       // 8 / GIMG
#define GWIN (GIMG * 25)          // 50 windows per group
#define MG   (GWIN * LW)          // 9800 rows per group
#define MLPCH 8192                // MLP chunk rows

typedef short bf16x8 __attribute__((ext_vector_type(8)));
typedef float f32x4  __attribute__((ext_vector_type(4)));

static __device__ __forceinline__ short f2bf(float f) {
  union { float f; uint32_t u; } v; v.f = f;
  uint32_t r = (v.u + 0x7fffu + ((v.u >> 16) & 1u)) >> 16;
  return (short)(uint16_t)r;
}
static __device__ __forceinline__ float bf2f(short s) {
  union { uint32_t u; float f; } v; v.u = ((uint32_t)(uint16_t)s) << 16;
  return v.f;
}

// async global->LDS, 16B per lane; lds base must be wave-uniform.
static __device__ __forceinline__ void async16(void* lds, const void* g) {
  __builtin_amdgcn_global_load_lds(
      (const __attribute__((address_space(1))) uint32_t*)g,
      (__attribute__((address_space(3))) uint32_t*)lds, 16, 0, 0);
}

// ---- weight transpose + cvt: in fp32 (K,N) row-major -> out bf16 (N,K) ----
__global__ __launch_bounds__(256) void k_transpose_cvt(
    const float* __restrict__ in, short* __restrict__ out, int K, int N) {
  __shared__ float t[32][33];
  int tx = threadIdx.x & 31, ty = threadIdx.x >> 5;   // ty 0..7
  int n0 = blockIdx.x * 32, k0 = blockIdx.y * 32;
#pragma unroll
  for (int i = 0; i < 4; ++i)
    t[ty + i * 8][tx] = in[(size_t)(k0 + ty + i * 8) * N + n0 + tx];
  __syncthreads();
#pragma unroll
  for (int i = 0; i < 4; ++i)
    out[(size_t)(n0 + ty + i * 8) * K + k0 + tx] = f2bf(t[tx][ty + i * 8]);
}

// ---- LayerNorm (wave per token). WINDOWED: emit window-partitioned+padded rows ----
template <bool WINDOWED>
__global__ __launch_bounds__(256) void k_layernorm(
    const float* __restrict__ in, const float* __restrict__ gw,
    const float* __restrict__ gb, short* __restrict__ out, int img0) {
  int wave = threadIdx.x >> 6, lane = threadIdx.x & 63;
  int t = blockIdx.x * 4 + wave;
  bool valid = true;
  size_t src;
  if (WINDOWED) {
    int win = t / LW, l = t % LW;              // win local to group
    int bi = img0 + win / 25, rem = win % 25;
    int y = (rem / 5) * 14 + l / 14;
    int x = (rem % 5) * 14 + l % 14;
    valid = (y < 64) && (x < 64);
    src = ((size_t)bi * 4096 + (size_t)y * 64 + x) * CDIM;
  } else {
    src = (size_t)t * CDIM;
  }
  size_t dst = (size_t)t * CDIM;
  if (valid) {
    float v[12];
    float s = 0.f, sq = 0.f;
#pragma unroll
    for (int j = 0; j < 3; ++j) {
      float4 f = *(const float4*)&in[src + (size_t)(j * 64 + lane) * 4];
      v[j * 4 + 0] = f.x; v[j * 4 + 1] = f.y; v[j * 4 + 2] = f.z; v[j * 4 + 3] = f.w;
      s += f.x + f.y + f.z + f.w;
      sq += f.x * f.x + f.y * f.y + f.z * f.z + f.w * f.w;
    }
#pragma unroll
    for (int m = 1; m < 64; m <<= 1) { s += __shfl_xor(s, m); sq += __shfl_xor(sq, m); }
    float mean = s * (1.f / 768.f);
    float rstd = rsqrtf(sq * (1.f / 768.f) - mean * mean + 1e-5f);
#pragma unroll
    for (int j = 0; j < 3; ++j) {
      int e = (j * 64 + lane) * 4;
      float4 w4 = *(const float4*)&gw[e];
      float4 b4 = *(const float4*)&gb[e];
      uint2 pk;
      pk.x = (uint32_t)(uint16_t)f2bf((v[j*4+0] - mean) * rstd * w4.x + b4.x)
           | ((uint32_t)(uint16_t)f2bf((v[j*4+1] - mean) * rstd * w4.y + b4.y) << 16);
      pk.y = (uint32_t)(uint16_t)f2bf((v[j*4+2] - mean) * rstd * w4.z + b4.z)
           | ((uint32_t)(uint16_t)f2bf((v[j*4+3] - mean) * rstd * w4.w + b4.w) << 16);
      *(uint2*)&out[dst + e] = pk;
    }
  } else {
    uint2 z; z.x = 0u; z.y = 0u;
#pragma unroll
    for (int j = 0; j < 3; ++j)
      *(uint2*)&out[dst + (size_t)(j * 64 + lane) * 4] = z;
  }
}

// ---- TN GEMM: C(M,N) = A(M,K)bf16 @ Bt(N,K)bf16^T + bias, m97 structure ----
// MODE 0: store bf16                               (QKV)
// MODE 1: unpad-scatter, +extra resid, store fp32  (proj; img0 = group image base)
// MODE 2: GELU(exact), store bf16                  (MLP1)
// MODE 3: +extra resid, store fp32                 (MLP2 -> d_out; out/extra alias same index, safe)
template <int MODE>
__global__ __launch_bounds__(256, 2) void k_gemm(
    const short* __restrict__ A, const short* __restrict__ Bt,
    const float* __restrict__ bias, void* __restrict__ out,
    const float* __restrict__ extra, int M, int N, int K, int img0) {
  __shared__ short As[128 * 32];
  __shared__ short Bs[128 * 32];
  int tid = threadIdx.x;
  int wave = tid >> 6, lane = tid & 63;
  int wm = wave >> 1, wn = wave & 1;
  int ln = lane & 15, q8 = (lane >> 4) * 8;
  long bm = (long)blockIdx.y * 128, bn = (long)blockIdx.x * 128;
  f32x4 acc[4][4];
#pragma unroll
  for (int i = 0; i < 4; ++i)
#pragma unroll
    for (int j = 0; j < 4; ++j) acc[i][j] = f32x4{0.f, 0.f, 0.f, 0.f};
  int srow = lane >> 2;          // 0..15
  int scol = (lane & 3) * 8;     // 0,8,16,24
  for (int k0 = 0; k0 < K; k0 += 32) {
#pragma unroll
    for (int i = 0; i < 2; ++i) {
      int chunk = wave * 2 + i;
      long ra = bm + chunk * 16 + srow;
      if (ra > M - 1) ra = M - 1;               // clamp (dup rows; never stored)
      async16(&As[chunk * 512], A + ra * K + k0 + scol);
      long rb = bn + chunk * 16 + srow;         // N is multiple of 128
      async16(&Bs[chunk * 512], Bt + rb * K + k0 + scol);
    }
    __syncthreads();
    bf16x8 af[4], bfv[4];
#pragma unroll
    for (int t = 0; t < 4; ++t) {
      af[t]  = *(const bf16x8*)&As[(wm * 64 + t * 16 + ln) * 32 + q8];
      bfv[t] = *(const bf16x8*)&Bs[(wn * 64 + t * 16 + ln) * 32 + q8];
    }
#pragma unroll
    for (int mt = 0; mt < 4; ++mt)
#pragma unroll
      for (int nt = 0; nt < 4; ++nt)
        acc[mt][nt] = __builtin_amdgcn_mfma_f32_16x16x32_bf16(af[mt], bfv[nt], acc[mt][nt], 0, 0, 0);
    __syncthreads();
  }
  // epilogue: C row = (lane>>4)*4 + r, col = lane&15  [measured layout, m89/m91]
#pragma unroll
  for (int nt = 0; nt < 4; ++nt) {
    int col = (int)(bn + wn * 64 + nt * 16 + ln);
    float bb = bias[col];
#pragma unroll
    for (int mt = 0; mt < 4; ++mt) {
#pragma unroll
      for (int r = 0; r < 4; ++r) {
        long row = bm + wm * 64 + mt * 16 + (lane >> 4) * 4 + r;
        if (row >= M) continue;
        float v = acc[mt][nt][r] + bb;
        if (MODE == 0) {
          ((short*)out)[row * (long)N + col] = f2bf(v);
        } else if (MODE == 1) {
          int win = (int)(row / LW), l = (int)(row % LW);
          int bi = img0 + win / 25, rem = win % 25;
          int y = (rem / 5) * 14 + l / 14;
          int x = (rem % 5) * 14 + l % 14;
          if (y < 64 && x < 64) {
            size_t d = ((size_t)bi * 4096 + (size_t)y * 64 + x) * CDIM + col;
            ((float*)out)[d] = v + extra[d];
          }
        } else if (MODE == 2) {
          v = 0.5f * v * (1.f + erff(v * 0.70710678118f));
          ((short*)out)[row * (long)N + col] = f2bf(v);
        } else {
          size_t d = (size_t)row * N + col;
          ((float*)out)[d] = v + extra[d];
        }
      }
    }
  }
}

// ---- attention v3: one block per (window, head); 4 waves; LDS 62256B ----
// Rel-pos bias computed in-kernel via MFMA: QRh = Q@Rh^T, QRw = Q@Rw^T (per
// wave's 16 q-rows), round-tripped through per-wave LDS tiles; gather
// bias = QRh[q][qh-kh+13] + QRw[q][qw-kw+13].
// LDS layout (shorts):
//   [0 .. 13720)        staging Vrm 196x70   -> later Ps: 4 waves x 16x208 (13312)
//   [13720 .. 27032)    Vt: 64x208
//   [27032 .. 31128)    BT: 4 waves x (QRh 16x32 | QRw 16x32)
__global__ __launch_bounds__(256, 2) void k_attn(
    const short* __restrict__ qkv, const float* __restrict__ relh,
    const float* __restrict__ relw, short* __restrict__ o) {
  __shared__ short lds[31128];
  short* PsBase = lds;
  short* Vrm    = lds;
  short* Vt     = lds + 13720;
  short* BT     = lds + 27032;
  int tid = threadIdx.x;
  int w = blockIdx.x / 12, h = blockIdx.x % 12;
  int wave = tid >> 6, lane = tid & 63;
  int ln = lane & 15, quad = lane >> 4;
  size_t qbase = (size_t)w * LW * 2304 + (size_t)h * 64;
  size_t kbase = qbase + 768;
  size_t vbase = qbase + 1536;

  // stage V row-major into Vrm (stride 70; b32 writes, 4B-aligned always)
  for (int i = tid; i < LW * 8; i += 256) {
    int row = i >> 3, c = (i & 7) * 8;
    uint4 f = *(const uint4*)&qkv[vbase + (size_t)row * 2304 + c];
    uint32_t* dst = (uint32_t*)&Vrm[row * 70 + c];
    dst[0] = f.x; dst[1] = f.y; dst[2] = f.z; dst[3] = f.w;
  }
  // load Rh/Rw B-fragments (rows = table idx 0..31, rows>=27 zero; fp32->bf16)
  bf16x8 rhf[2][2], rwf[2][2];
#pragma unroll
  for (int nt2 = 0; nt2 < 2; ++nt2) {
    int trow = nt2 * 16 + ln;
#pragma unroll
    for (int kk = 0; kk < 2; ++kk) {
      bf16x8 fh = bf16x8{0,0,0,0,0,0,0,0};
      bf16x8 fw = fh;
      if (trow < 27) {
        const float* ph = &relh[trow * 64 + kk * 32 + quad * 8];
        const float* pw = &relw[trow * 64 + kk * 32 + quad * 8];
#pragma unroll
        for (int j = 0; j < 8; ++j) { fh[j] = f2bf(ph[j]); fw[j] = f2bf(pw[j]); }
      }
      rhf[nt2][kk] = fh; rwf[nt2][kk] = fw;
    }
  }
  __syncthreads();
  // transpose: Vt[d*208+l] = Vrm[l*70+d]; read stride 35 dwords -> conflict-free
  for (int i = tid; i < 64 * 208; i += 256) {
    int d = i / 208, l = i % 208;
    Vt[i] = (l < LW) ? Vrm[l * 70 + d] : (short)0;
  }
  __syncthreads();

  short* Ps  = PsBase + wave * (16 * 208);
  short* BTh = BT + wave * 1024;     // 16x32
  short* BTw = BTh + 512;            // 16x32
  const float scale = 0.125f;
  for (int mt = wave; mt < 13; mt += 4) {
    bf16x8 aq[2];
    int qrow = mt * 16 + ln; if (qrow > LW - 1) qrow = LW - 1;
#pragma unroll
    for (int kk = 0; kk < 2; ++kk)
      aq[kk] = *(const bf16x8*)&qkv[qbase + (size_t)qrow * 2304 + kk * 32 + quad * 8];
    f32x4 s[13];
#pragma unroll
    for (int nt = 0; nt < 13; ++nt) {
      s[nt] = f32x4{0.f, 0.f, 0.f, 0.f};
      int krow = nt * 16 + ln; if (krow > LW - 1) krow = LW - 1;
#pragma unroll
      for (int kk = 0; kk < 2; ++kk) {
        bf16x8 bk = *(const bf16x8*)&qkv[kbase + (size_t)krow * 2304 + kk * 32 + quad * 8];
        s[nt] = __builtin_amdgcn_mfma_f32_16x16x32_bf16(aq[kk], bk, s[nt], 0, 0, 0);
      }
    }
    // bias tiles for this wave's q-rows: QRh/QRw (16x32 each) -> private LDS
    {
      f32x4 bh_t[2], bw_t[2];
#pragma unroll
      for (int nt2 = 0; nt2 < 2; ++nt2) {
        bh_t[nt2] = f32x4{0.f, 0.f, 0.f, 0.f};
        bw_t[nt2] = f32x4{0.f, 0.f, 0.f, 0.f};
#pragma unroll
        for (int kk = 0; kk < 2; ++kk) {
          bh_t[nt2] = __builtin_amdgcn_mfma_f32_16x16x32_bf16(aq[kk], rhf[nt2][kk], bh_t[nt2], 0, 0, 0);
          bw_t[nt2] = __builtin_amdgcn_mfma_f32_16x16x32_bf16(aq[kk], rwf[nt2][kk], bw_t[nt2], 0, 0, 0);
        }
#pragma unroll
        for (int r = 0; r < 4; ++r) {
          int rowi = quad * 4 + r;
          BTh[rowi * 32 + nt2 * 16 + ln] = f2bf(bh_t[nt2][r]);
          BTw[rowi * 32 + nt2 * 16 + ln] = f2bf(bw_t[nt2][r]);
        }
      }
    }
    // scale + bias (from LDS tiles) + mask; then row softmax
    float rmax[4] = {-3e38f, -3e38f, -3e38f, -3e38f};
#pragma unroll
    for (int nt = 0; nt < 13; ++nt) {
      int c = nt * 16 + ln;
      int cc = c > LW - 1 ? LW - 1 : c;
      int cdiv = (cc * 4682) >> 16;      // cc/14
      int cmod = cc - cdiv * 14;
#pragma unroll
      for (int r = 0; r < 4; ++r) {
        int rowi = quad * 4 + r;
        int q = mt * 16 + rowi;
        int qc = q > LW - 1 ? LW - 1 : q;
        int qh = (qc * 4682) >> 16;
        int qw = qc - qh * 14;
        float bias = bf2f(BTh[rowi * 32 + (qh - cdiv + 13)])
                   + bf2f(BTw[rowi * 32 + (qw - cmod + 13)]);
        float v;
        if (c < LW && q < LW)
          v = s[nt][r] * scale + bias;
        else
          v = -1e30f;
        s[nt][r] = v;
        rmax[r] = fmaxf(rmax[r], v);
      }
    }
#pragma unroll
    for (int r = 0; r < 4; ++r)
#pragma unroll
      for (int m = 1; m < 16; m <<= 1) rmax[r] = fmaxf(rmax[r], __shfl_xor(rmax[r], m));
    float rsum[4] = {0.f, 0.f, 0.f, 0.f};
#pragma unroll
    for (int nt = 0; nt < 13; ++nt)
#pragma unroll
      for (int r = 0; r < 4; ++r) {
        float e = __expf(s[nt][r] - rmax[r]);
        s[nt][r] = e;
        rsum[r] += e;
      }
#pragma unroll
    for (int r = 0; r < 4; ++r) {
#pragma unroll
      for (int m = 1; m < 16; m <<= 1) rsum[r] += __shfl_xor(rsum[r], m);
      rsum[r] = 1.f / rsum[r];
    }
    // P tile -> LDS (bf16), cols 0..207 all written (>=196 are exp(-inf)=0)
#pragma unroll
    for (int nt = 0; nt < 13; ++nt) {
      int c = nt * 16 + ln;
#pragma unroll
      for (int r = 0; r < 4; ++r) {
        int rowi = quad * 4 + r;
        int q = mt * 16 + rowi;
        float p = (q < LW) ? s[nt][r] * rsum[r] : 0.f;
        Ps[rowi * 208 + c] = f2bf(p);
      }
    }
    // PV: O(16x64) += P(16x208) @ V^T(208x64); intra-wave LDS RAW (in-order LDS)
    f32x4 acc[4];
#pragma unroll
    for (int nt = 0; nt < 4; ++nt) acc[nt] = f32x4{0.f, 0.f, 0.f, 0.f};
#pragma unroll
    for (int ks = 0; ks < 6; ++ks) {
      bf16x8 ap = *(const bf16x8*)&Ps[ln * 208 + ks * 32 + quad * 8];
#pragma unroll
      for (int nt = 0; nt < 4; ++nt) {
        bf16x8 bv = *(const bf16x8*)&Vt[(nt * 16 + ln) * 208 + ks * 32 + quad * 8];
        acc[nt] = __builtin_amdgcn_mfma_f32_16x16x32_bf16(ap, bv, acc[nt], 0, 0, 0);
      }
    }
    {
      // tail: cols 192..207 = k 0..15 of a 32-wide step -> quads 0,1 real, quads 2,3 zero
      bf16x8 zz = bf16x8{0,0,0,0,0,0,0,0};
      bf16x8 ap = (quad < 2) ? *(const bf16x8*)&Ps[ln * 208 + 192 + quad * 8] : zz;
#pragma unroll
      for (int nt = 0; nt < 4; ++nt) {
        bf16x8 bv = (quad < 2) ? *(const bf16x8*)&Vt[(nt * 16 + ln) * 208 + 192 + quad * 8] : zz;
        acc[nt] = __builtin_amdgcn_mfma_f32_16x16x32_bf16(ap, bv, acc[nt], 0, 0, 0);
      }
    }
#pragma unroll
    for (int nt = 0; nt < 4; ++nt)
#pragma unroll
      for (int r = 0; r < 4; ++r) {
        int q = mt * 16 + quad * 4 + r;
        if (q < LW)
          o[((size_t)w * LW + q) * CDIM + (size_t)h * 64 + nt * 16 + ln] = f2bf(acc[nt][r]);
      }
  }
}

extern "C" void kernel_launch(void* const* d_in, const int* in_sizes, int n_in,
                              void* d_out, int out_size, void* d_ws, size_t ws_size,
                              hipStream_t stream) {
  const float* x     = (const float*)d_in[0];
  const float* ln1w  = (const float*)d_in[1];
  const float* ln1b  = (const float*)d_in[2];
  const float* qkvw  = (const float*)d_in[3];
  const float* qkvb  = (const float*)d_in[4];
  const float* projw = (const float*)d_in[5];
  const float* projb = (const float*)d_in[6];
  const float* relh  = (const float*)d_in[7];
  const float* relw  = (const float*)d_in[8];
  const float* ln2w  = (const float*)d_in[9];
  const float* ln2b  = (const float*)d_in[10];
  const float* mlpw1 = (const float*)d_in[11];
  const float* mlpb1 = (const float*)d_in[12];
  const float* mlpw2 = (const float*)d_in[13];
  const float* mlpb2 = (const float*)d_in[14];

  char* ws = (char*)d_ws;
  size_t off = 0;
  auto alloc = [&](size_t bytes) {
    char* p = ws + off;
    off += (bytes + 255) & ~(size_t)255;
    return p;
  };
  // persistent weights (bf16, transposed)           ~14.2 MB
  short* wQKVt  = (short*)alloc((size_t)2304 * 768 * 2);
  short* wPROJt = (short*)alloc((size_t)768 * 768 * 2);
  short* wMLP1t = (short*)alloc((size_t)3072 * 768 * 2);
  short* wMLP2t = (short*)alloc((size_t)768 * 3072 * 2);
  // group loop region (reused per group; later aliased by MLP1 chunk)  ~60 MB
  char* loopBase = alloc((size_t)MG * CDIM * 2        // A_g / O_g
                       + (size_t)MG * 2304 * 2);      // QKV_g
  short* wA    = (short*)loopBase;
  short* wQKV  = (short*)(loopBase + (size_t)MG * CDIM * 2);
  short* wO    = wA;                                  // O_g aliases A_g (dead after QKV GEMM)
  short* wMLP1 = (short*)loopBase;                    // MLP1 chunk aliases loop region (dead)
  // LN2 output (full batch)                          ~50.3 MB
  short* wH2  = (short*)alloc((size_t)NTOK * CDIM * 2);
  // fp32 residual x2 lives in d_out (exact size match; MODE-3 aliasing is same-index safe)
  float* wX2  = (float*)d_out;

  k_transpose_cvt<<<dim3(2304 / 32, 768 / 32), 256, 0, stream>>>(qkvw, wQKVt, 768, 2304);
  k_transpose_cvt<<<dim3(768 / 32, 768 / 32), 256, 0, stream>>>(projw, wPROJt, 768, 768);
  k_transpose_cvt<<<dim3(3072 / 32, 768 / 32), 256, 0, stream>>>(mlpw1, wMLP1t, 768, 3072);
  k_transpose_cvt<<<dim3(768 / 32, 3072 / 32), 256, 0, stream>>>(mlpw2, wMLP2t, 3072, 768);

  for (int g = 0; g < NGRP; ++g) {
    int img0 = g * GIMG;
    k_layernorm<true><<<MG / 4, 256, 0, stream>>>(x, ln1w, ln1b, wA, img0);
    k_gemm<0><<<dim3(2304 / 128, (MG + 127) / 128), 256, 0, stream>>>(
        wA, wQKVt, qkvb, wQKV, nullptr, MG, 2304, 768, 0);
    k_attn<<<GWIN * 12, 256, 0, stream>>>(wQKV, relh, relw, wO);
    k_gemm<1><<<dim3(768 / 128, (MG + 127) / 128), 256, 0, stream>>>(
        wO, wPROJt, projb, wX2, x, MG, 768, 768, img0);
  }

  k_layernorm<false><<<NTOK / 4, 256, 0, stream>>>(wX2, ln2w, ln2b, wH2, 0);

  for (int c = 0; c < NTOK / MLPCH; ++c) {
    const short* h2c = wH2 + (size_t)c * MLPCH * CDIM;
    float* outc = (float*)d_out + (size_t)c * MLPCH * CDIM;
    k_gemm<2><<<dim3(3072 / 128, MLPCH / 128), 256, 0, stream>>>(
        h2c, wMLP1t, mlpb1, wMLP1, nullptr, MLPCH, 3072, 768, 0);
    k_gemm<3><<<dim3(768 / 128, MLPCH / 128), 256, 0, stream>>>(
        wMLP1, wMLP2t, mlpb2, outc, outc, MLPCH, 768, 3072, 0);
  }
}